// Round 7
// baseline (4837.264 us; speedup 1.0000x reference)
//
#include <hip/hip_runtime.h>
#include <hip/hip_bf16.h>

// NRDE layer (all I/O fp32):
//   A2[a][b][c] : c<NC -> A[h*256+w] = sum_d ml_w[w,h*136+d]*logsig[b,a,1+d]
//                 c>=NC -> bias[h]   = sum_d ml_b[h*136+d]  *logsig[b,a,1+d]
//   (MFMA GEMM chunked so each As chunk fits the 256MB L3: C<=20 -> 168MB;
//    agemm writes absorbed by memory-side Infinity Cache, scan reads hit L3)
//   scan: 1 block (512 thr) per batch element, RK2; weights streamed bf16-packed,
//   wave-local K-split + shfl_xor reductions -> 4 barriers/eval.
//
// LESSONS: (r3-5) register-resident weights spill (backend VGPR-occupancy cap).
// (r6) 1024 thr -> 64-VGPR cap -> A-prefetch spilled (WRITE 49MB canary) ->
// latency + L2 pollution. 512 thr keeps VGPR<=128 honest. C=64 -> 539MB As
// chunk > L3 -> strided HBM writes killed agemm (~1.7ms).

#define BB 128
#define SS 64
#define LL 137
#define HH 128
#define DIN 64
#define WW 256
#define DD 136
#define KP 160
#define NC 32768
#define NCR 32896
#define AST 40
#define CMAX 20             // As chunk cap: 20*8.42MB = 168MB < 256MB L3
#define OUT2_OFF ((size_t)BB*(SS+1)*HH)

typedef __hip_bfloat16 bf16;
typedef __attribute__((ext_vector_type(8))) short short8;
typedef __attribute__((ext_vector_type(4))) float f32x4;

__device__ __forceinline__ float bf2f(bf16 x) { return __bfloat162float(x); }
__device__ __forceinline__ bf16  f2bf(float x){ return __float2bfloat16(x); }
__device__ __forceinline__ float2 upk(unsigned u){
  float2 r;
  r.x = __uint_as_float(u << 16);
  r.y = __uint_as_float(u & 0xffff0000u);
  return r;
}
__device__ __forceinline__ unsigned pk2(float a, float b){
  bf16 lo = f2bf(a), hi = f2bf(b);
  return (unsigned)*(unsigned short*)&lo | ((unsigned)*(unsigned short*)&hi << 16);
}
__device__ __forceinline__ float tanh_fast(float v){
  float vc = fminf(fmaxf(v, -9.f), 9.f);
  float e = __expf(2.f*vc);
  return (e - 1.f) * __builtin_amdgcn_rcpf(e + 1.f);
}

// ---------------- prep: coeff rows m=a*128+b (fp32 -> bf16), K padded ----------------
__global__ void prep_coeff(const float* __restrict__ logsig, bf16* __restrict__ cA){
  int m = blockIdx.x, d = threadIdx.x;
  int a = m >> 7, b = m & 127;
  float v = 0.0f;
  if (d < DD) v = logsig[(size_t)(b*SS + a)*LL + 1 + d];
  cA[(size_t)m*KP + d] = f2bf(v);
}

// ---------------- prep: btt[c][d]; c<NC: ml_w[w][h*136+d] (c=h*256+w); c>=NC: ml_b ----------------
__global__ void prep_btt(const float* __restrict__ mlw, const float* __restrict__ mlb,
                         bf16* __restrict__ btt){
  int c = blockIdx.x, d = threadIdx.x;
  float v = 0.0f;
  if (d < DD){
    if (c < NC){
      int h = c >> 8, w = c & 255;
      v = mlw[(size_t)w*(HH*DD) + h*DD + d];
    } else {
      v = mlb[(size_t)(c - NC)*DD + d];
    }
  }
  btt[(size_t)c*KP + d] = f2bf(v);
}

// ---------------- prep: pack weights lane-major for the scan's (j=t>>1, kh=t&1) mapping ----------------
// w1q[i*512 + t] packs k = kh*64 + 4i .. +3 (i<16); w2q/w3q: k = kh*128 + 4i (i<32).
__global__ void prep_wpack(const float* __restrict__ h1w, const float* __restrict__ h2w,
                           const float* __restrict__ vow,
                           uint2* __restrict__ w1q, uint2* __restrict__ w2q,
                           uint2* __restrict__ w3q){
  int bi = blockIdx.x, t = threadIdx.x;
  int j = t >> 1, kh = t & 1;
  if (bi < 16){
    int i = bi, k0 = kh*64 + 4*i;
    w1q[i*512 + t] = make_uint2(
      pk2(h1w[(size_t)k0*WW + j],     h1w[(size_t)(k0+1)*WW + j]),
      pk2(h1w[(size_t)(k0+2)*WW + j], h1w[(size_t)(k0+3)*WW + j]));
  } else if (bi < 48){
    int i = bi - 16, k0 = kh*128 + 4*i;
    w2q[i*512 + t] = make_uint2(
      pk2(h2w[(size_t)k0*WW + j],     h2w[(size_t)(k0+1)*WW + j]),
      pk2(h2w[(size_t)(k0+2)*WW + j], h2w[(size_t)(k0+3)*WW + j]));
  } else {
    int i = bi - 48, k0 = kh*128 + 4*i;
    w3q[i*512 + t] = make_uint2(
      pk2(vow[(size_t)k0*WW + j],     vow[(size_t)(k0+1)*WW + j]),
      pk2(vow[(size_t)(k0+2)*WW + j], vow[(size_t)(k0+3)*WW + j]));
  }
}

// ---------------- A-GEMM: 64x128 tile, 256 thr, 4 waves (proven structure) ----------------
__global__ __launch_bounds__(256) void agemm_kernel(const bf16* __restrict__ cA,
                                                    const bf16* __restrict__ btt,
                                                    bf16* __restrict__ As, int mAbs0){
  __shared__ __align__(16) short a_sm[64*AST];
  __shared__ __align__(16) short b_sm[128*AST];
  __shared__ __align__(16) short o_sm[64*136];
  int mt = blockIdx.x, nt = blockIdx.y;
  int t = threadIdx.x, lane = t & 63, wid = t >> 6;
  int mBlockAbs = mAbs0 + mt*64;
  int c0 = nt*128;
  int mW = (wid & 1)*32, cW = (wid >> 1)*64;

  f32x4 acc[2][4];
  for (int i = 0; i < 2; ++i)
    for (int j = 0; j < 4; ++j)
      acc[i][j] = (f32x4){0.f,0.f,0.f,0.f};

  for (int kk = 0; kk < 5; ++kk){
    int d0 = kk*32;
    {
      int row = t >> 2, seg = t & 3;
      uint4 v = *(const uint4*)(cA + (size_t)(mBlockAbs+row)*KP + d0 + seg*8);
      *(uint4*)&a_sm[row*AST + seg*8] = v;
    }
    #pragma unroll
    for (int rep = 0; rep < 2; ++rep){
      int idx = t + rep*256;
      int row = idx >> 2, seg = idx & 3;
      uint4 v = *(const uint4*)(btt + (size_t)(c0+row)*KP + d0 + seg*8);
      *(uint4*)&b_sm[row*AST + seg*8] = v;
    }
    __syncthreads();
    int mr = lane & 15, q = lane >> 4;
    short8 af0 = *(const short8*)&a_sm[(mW + mr)*AST + q*8];
    short8 af1 = *(const short8*)&a_sm[(mW + 16 + mr)*AST + q*8];
    #pragma unroll
    for (int ci = 0; ci < 4; ++ci){
      short8 bfr = *(const short8*)&b_sm[(cW + ci*16 + mr)*AST + q*8];
      acc[0][ci] = __builtin_amdgcn_mfma_f32_16x16x32_bf16(af0, bfr, acc[0][ci], 0, 0, 0);
      acc[1][ci] = __builtin_amdgcn_mfma_f32_16x16x32_bf16(af1, bfr, acc[1][ci], 0, 0, 0);
    }
    __syncthreads();
  }

  {
    int mr = lane & 15, q = lane >> 4;
    #pragma unroll
    for (int mi = 0; mi < 2; ++mi)
      #pragma unroll
      for (int ci = 0; ci < 4; ++ci){
        int col = cW + ci*16 + mr;
        #pragma unroll
        for (int r = 0; r < 4; ++r){
          int row = mW + mi*16 + q*4 + r;
          bf16 bv = f2bf(acc[mi][ci][r]);
          o_sm[row*136 + col] = *(short*)&bv;
        }
      }
  }
  __syncthreads();
  int mLocBlock = mt*64;
  #pragma unroll
  for (int rep = 0; rep < 4; ++rep){
    int idx = t + rep*256;
    int row = idx >> 4, seg = idx & 15;
    uint4 v = *(const uint4*)&o_sm[row*136 + seg*8];
    *(uint4*)(As + (size_t)(mLocBlock + row)*NCR + c0 + seg*8) = v;
  }
}

// ---------------- scan: 1 block / batch element, 512 threads, shfl reductions ----------------
#define AMAC(u, o) { float2 p; \
  p = upk(u.x); s += hv[(o)+0]*p.x + hv[(o)+1]*p.y; \
  p = upk(u.y); s += hv[(o)+2]*p.x + hv[(o)+3]*p.y; \
  p = upk(u.z); s += hv[(o)+4]*p.x + hv[(o)+5]*p.y; \
  p = upk(u.w); s += hv[(o)+6]*p.x + hv[(o)+7]*p.y; }

__global__ __launch_bounds__(512, 1) void scan_kernel(
    const float* __restrict__ times, const float* __restrict__ initial,
    const float* __restrict__ in_w, const float* __restrict__ in_b,
    const float* __restrict__ h1_b, const float* __restrict__ h2_b,
    const float* __restrict__ vo_b,
    const uint2* __restrict__ w1q, const uint2* __restrict__ w2q,
    const uint2* __restrict__ w3q,
    const bf16* __restrict__ As,
    float* __restrict__ y_state, float* __restrict__ out,
    int s0, int s1, int aBase)
{
  const int b = blockIdx.x, t = threadIdx.x;
  const int j = t >> 1, kh = t & 1;        // MLP: column j, K-half kh (wave-local pair)
  const int h = t >> 2, q = t & 3;         // matvec: row h, w-quarter q (wave-local quad)
  __shared__ __align__(16) float yv[HH], ytmp[HH], bufA[WW], bufB[WW], kk1[HH];

  const float b1 = h1_b[j], b2 = h2_b[j], b3 = vo_b[j];

  if (s0 == 0){
    if (t < HH){
      float acc = in_b[t];
      for (int i = 0; i < DIN; ++i)
        acc += initial[b*DIN + i] * in_w[(size_t)i*HH + t];
      yv[t] = acc;
      out[((size_t)b*(SS+1))*HH + t] = acc;
    }
  } else {
    if (t < HH) yv[t] = y_state[b*HH + t];
  }
  __syncthreads();

  for (int n = s0; n < s1; ++n){
    float t0 = times[n], t1 = times[n+1];
    float dt = t1 - t0;
    int idx1 = (n >= 1) ? n : 1;
    float inv1 = 1.f/(times[idx1] - times[idx1-1]);
    float inv2 = 1.f/dt;
    int a1 = ((n >= 1) ? (n-1) : 0) - aBase;
    int a2 = n - aBase;

    #pragma unroll 1
    for (int ev = 0; ev < 2; ++ev){
      const float* yin = (ev == 0) ? yv : ytmp;
      int aLoc = (ev == 0) ? a1 : a2;
      float inv_dtf = (ev == 0) ? inv1 : inv2;

      // prefetch A slice (64 w per thread, contiguous per wave) + bias (q==0 lanes)
      const bf16* Abase = As + ((size_t)aLoc*BB + b)*NCR;
      const bf16* Arow = Abase + h*WW + q*64;
      uint4 u0 = *(const uint4*)(Arow +  0);
      uint4 u1 = *(const uint4*)(Arow +  8);
      uint4 u2 = *(const uint4*)(Arow + 16);
      uint4 u3 = *(const uint4*)(Arow + 24);
      uint4 u4 = *(const uint4*)(Arow + 32);
      uint4 u5 = *(const uint4*)(Arow + 40);
      uint4 u6 = *(const uint4*)(Arow + 48);
      uint4 u7 = *(const uint4*)(Arow + 56);
      float biasv = (q == 0) ? bf2f(Abase[NC + h]) : 0.f;

      // L1: 128 -> 256 relu (K-half = 64 vals = 16 uint2)
      {
        float acc = 0.f;
        const float4* xv = (const float4*)(yin + kh*64);
        const uint2* wp = w1q + t;
        #pragma unroll
        for (int i = 0; i < 16; ++i){
          uint2 u = wp[i*512];
          float4 f = xv[i];
          float2 p0 = upk(u.x), p1 = upk(u.y);
          acc += f.x*p0.x + f.y*p0.y + f.z*p1.x + f.w*p1.y;
        }
        acc += __shfl_xor(acc, 1);
        if (kh == 0){ float v = b1 + acc; bufA[j] = v > 0.f ? v : 0.f; }
      }
      __syncthreads();
      // L2: 256 -> 256 relu (K-half = 128 vals = 32 uint2)
      {
        float acc = 0.f;
        const float4* xv = (const float4*)(bufA + kh*128);
        const uint2* wp = w2q + t;
        #pragma unroll
        for (int i = 0; i < 32; ++i){
          uint2 u = wp[i*512];
          float4 f = xv[i];
          float2 p0 = upk(u.x), p1 = upk(u.y);
          acc += f.x*p0.x + f.y*p0.y + f.z*p1.x + f.w*p1.y;
        }
        acc += __shfl_xor(acc, 1);
        if (kh == 0){ float v = b2 + acc; bufB[j] = v > 0.f ? v : 0.f; }
      }
      __syncthreads();
      // L3: 256 -> 256 tanh
      {
        float acc = 0.f;
        const float4* xv = (const float4*)(bufB + kh*128);
        const uint2* wp = w3q + t;
        #pragma unroll
        for (int i = 0; i < 32; ++i){
          uint2 u = wp[i*512];
          float4 f = xv[i];
          float2 p0 = upk(u.x), p1 = upk(u.y);
          acc += f.x*p0.x + f.y*p0.y + f.z*p1.x + f.w*p1.y;
        }
        acc += __shfl_xor(acc, 1);
        if (kh == 0) bufA[j] = tanh_fast(b3 + acc);
      }
      __syncthreads();
      // matvec + state update (lane q==0 of each quad owns row h)
      {
        const float* hv = bufA + q*64;
        float s = 0.f;
        AMAC(u0,  0) AMAC(u1,  8) AMAC(u2, 16) AMAC(u3, 24)
        AMAC(u4, 32) AMAC(u5, 40) AMAC(u6, 48) AMAC(u7, 56)
        s += __shfl_xor(s, 1);
        s += __shfl_xor(s, 2);
        if (q == 0){
          float kv = (s + biasv) * inv_dtf;
          if (ev == 0){
            kk1[h] = kv;
            ytmp[h] = yv[h] + dt*kv;
          } else {
            float ynew = yv[h] + 0.5f*dt*(kk1[h] + kv);
            yv[h] = ynew;
            out[((size_t)b*(SS+1) + (n+1))*HH + h] = ynew;
          }
        }
      }
      __syncthreads();
    }
  }

  if (t < HH){
    y_state[b*HH + t] = yv[t];
    if (s1 == SS) out[OUT2_OFF + (size_t)b*HH + t] = yv[t];
  }
}

extern "C" void kernel_launch(void* const* d_in, const int* in_sizes, int n_in,
                              void* d_out, int out_size, void* d_ws, size_t ws_size,
                              hipStream_t stream)
{
  (void)in_sizes; (void)n_in; (void)out_size;
  const float* times   = (const float*)d_in[0];
  const float* logsig  = (const float*)d_in[1];
  const float* initial = (const float*)d_in[2];
  const float* in_w    = (const float*)d_in[3];
  const float* in_b    = (const float*)d_in[4];
  const float* h1_w    = (const float*)d_in[5];
  const float* h1_b    = (const float*)d_in[6];
  const float* h2_w    = (const float*)d_in[7];
  const float* h2_b    = (const float*)d_in[8];
  const float* vo_w    = (const float*)d_in[9];
  const float* vo_b    = (const float*)d_in[10];
  const float* ml_w    = (const float*)d_in[11];
  const float* ml_b    = (const float*)d_in[12];
  float* out = (float*)d_out;

  char* ws = (char*)d_ws;
  size_t off = 0;
  bf16* cA      = (bf16*)(ws + off); off += (size_t)8192*KP*2;        // 2.62 MB
  bf16* btt     = (bf16*)(ws + off); off += (size_t)NCR*KP*2;         // 10.53 MB
  uint2* w1q    = (uint2*)(ws + off); off += (size_t)16*512*8;        // 64 KB
  uint2* w2q    = (uint2*)(ws + off); off += (size_t)32*512*8;        // 128 KB
  uint2* w3q    = (uint2*)(ws + off); off += (size_t)32*512*8;        // 128 KB
  float* y_state= (float*)(ws + off); off += (size_t)BB*HH*4;         // 64 KB
  bf16* As      = (bf16*)(ws + off);
  size_t perA = (size_t)BB*NCR*2;                                     // 8.42 MB per a-index
  size_t avail = (ws_size > off) ? (ws_size - off) : 0;
  int C = (int)(avail / perA);
  if (C > CMAX) C = CMAX;                                             // keep chunk L3-resident
  if (C < 2) return;

  prep_coeff<<<8192, 160, 0, stream>>>(logsig, cA);
  prep_btt<<<NCR, 160, 0, stream>>>(ml_w, ml_b, btt);
  prep_wpack<<<80, 512, 0, stream>>>(h1_w, h2_w, vo_w, w1q, w2q, w3q);

  int s = 0, aB = 0;
  while (s < SS){
    int cc = SS - aB; if (cc > C) cc = C;
    agemm_kernel<<<dim3(cc*2, 257), 256, 0, stream>>>(cA, btt, As, aB*BB);
    int sEnd = aB + cc; if (sEnd > SS) sEnd = SS;
    scan_kernel<<<BB, 512, 0, stream>>>(times, initial, in_w, in_b,
        h1_b, h2_b, vo_b, w1q, w2q, w3q, As, y_state, out, s, sEnd, aB);
    s = sEnd;
    aB = sEnd - 1;
  }
}